// Round 1
// baseline (10.127 us; speedup 1.0000x reference)
//
#include <hip/hip_runtime.h>
#include <hip/hip_bf16.h>

// Embedding gather: out[b,s,:] = weight[input_ids[b,s], :]
// ids: [4,2048] int32, weight: [32000,128] f32, out: [4,2048,128] f32.
// One float4 (4 floats) per thread: row has 128 floats = 32 float4s.
__global__ void embedding_gather_kernel(const int* __restrict__ ids,
                                        const float4* __restrict__ w4,
                                        float4* __restrict__ out4,
                                        int total_vec)  // total float4s = rows*32
{
    int t = blockIdx.x * blockDim.x + threadIdx.x;
    if (t >= total_vec) return;
    int row = t >> 5;        // which token
    int col = t & 31;        // which float4 within the 128-float row
    int id = ids[row];       // gathered vocab index
    out4[t] = w4[(long long)id * 32 + col];
}

extern "C" void kernel_launch(void* const* d_in, const int* in_sizes, int n_in,
                              void* d_out, int out_size, void* d_ws, size_t ws_size,
                              hipStream_t stream) {
    const int* ids = (const int*)d_in[0];          // [4*2048] int32
    const float4* w4 = (const float4*)d_in[1];     // [32000*128] f32 viewed as float4
    float4* out4 = (float4*)d_out;                 // [8192*128] f32 viewed as float4

    int rows = in_sizes[0];            // 8192 tokens
    int total_vec = rows * 32;         // 262144 float4s

    int block = 256;
    int grid = (total_vec + block - 1) / block;   // 1024 blocks
    embedding_gather_kernel<<<grid, block, 0, stream>>>(ids, w4, out4, total_vec);
}

// Round 2
// 9.785 us; speedup vs baseline: 1.0349x; 1.0349x over previous
//
#include <hip/hip_runtime.h>
#include <hip/hip_bf16.h>

// Embedding gather: out[b,s,:] = weight[input_ids[b,s], :]
// ids: [4,2048] int32, weight: [32000,128] f32, out: [4,2048,128] f32.
// ILP=4: each thread handles 4 float4 slots spaced `span` apart so that
// within each batch consecutive threads touch consecutive addresses
// (fully coalesced), and all 4 gathers are independent (4 loads in flight).
__global__ void embedding_gather_ilp4(const int* __restrict__ ids,
                                      const float4* __restrict__ w4,
                                      float4* __restrict__ out4,
                                      int total_vec,   // total float4s = rows*32
                                      int span)        // total_vec / 4
{
    int i = blockIdx.x * blockDim.x + threadIdx.x;
    if (i >= span) return;

    int t0 = i;
    int t1 = i + span;
    int t2 = i + 2 * span;
    int t3 = i + 3 * span;

    // Independent id loads (rows = t>>5), all issued before any use.
    int id0 = ids[t0 >> 5];
    int id1 = ids[t1 >> 5];
    int id2 = ids[t2 >> 5];
    int id3 = ids[t3 >> 5];

    // Independent gathers.
    float4 v0 = w4[(long long)id0 * 32 + (t0 & 31)];
    float4 v1 = w4[(long long)id1 * 32 + (t1 & 31)];
    float4 v2 = w4[(long long)id2 * 32 + (t2 & 31)];
    float4 v3 = w4[(long long)id3 * 32 + (t3 & 31)];

    out4[t0] = v0;
    out4[t1] = v1;
    out4[t2] = v2;
    out4[t3] = v3;
}

extern "C" void kernel_launch(void* const* d_in, const int* in_sizes, int n_in,
                              void* d_out, int out_size, void* d_ws, size_t ws_size,
                              hipStream_t stream) {
    const int* ids = (const int*)d_in[0];          // [8192] int32
    const float4* w4 = (const float4*)d_in[1];     // [32000*32] float4
    float4* out4 = (float4*)d_out;                 // [8192*32] float4

    int rows = in_sizes[0];            // 8192 tokens
    int total_vec = rows * 32;         // 262144 float4s
    int span = total_vec / 4;          // 65536 threads

    int block = 256;
    int grid = (span + block - 1) / block;   // 256 blocks
    embedding_gather_ilp4<<<grid, block, 0, stream>>>(ids, w4, out4, total_vec, span);
}